// Round 4
// baseline (122.366 us; speedup 1.0000x reference)
//
#include <hip/hip_runtime.h>

typedef __attribute__((ext_vector_type(8))) short short8;
typedef __attribute__((ext_vector_type(8))) _Float16 half8;
typedef __attribute__((ext_vector_type(4))) float floatx4;

constexpr int NB  = 2;
constexpr int CC  = 64;
constexpr int DD  = 16;
constexpr int HH  = 32;
constexpr int WW  = 32;
constexpr int KN_ = 27;
constexpr int KSP = 14;             // k-split point
constexpr int OC  = 64;
constexpr int DHW = DD * HH * WW;   // 16384
constexpr size_t OUT_ELEMS = (size_t)NB * OC * DHW;   // 2M f32

__device__ __forceinline__ unsigned short f2h(float f) {
    _Float16 h = (_Float16)f;
    return *(unsigned short*)&h;
}

// ---------------------------------------------------------------------------
// Prep kernel (merged):
//  blocks [0, 512)   : NCDHW f32 -> NDHWC f16  (64 ch contiguous per voxel)
//  blocks [512, 944) : weight (o,c,k) f32 -> f16 MFMA A-fragment stream
//    wf[(((k*2+cc)*4+wv)*64 + l)*8 + i] = W[o=wv*16+(l&15)][c=cc*32+(l>>4)*8+i][k]
__global__ __launch_bounds__(256) void k_prep(const float* __restrict__ in,
                                              const float* __restrict__ w,
                                              unsigned int* __restrict__ outu,
                                              unsigned short* __restrict__ wf) {
    int bid = blockIdx.x;
    int t = threadIdx.x;
    if (bid < 512) {
        __shared__ float tile[64][65];
        int n  = bid >> 8;
        int v0 = (bid & 255) << 6;
        int lane = t & 63, row = t >> 6;
#pragma unroll
        for (int i = 0; i < 16; ++i) {
            int c = (i << 2) + row;
            tile[c][lane] = in[(size_t)(n * CC + c) * DHW + v0 + lane];
        }
        __syncthreads();
#pragma unroll
        for (int i = 0; i < 8; ++i) {
            int flat = i * 256 + t;
            int v = flat >> 5, cd = flat & 31;
            unsigned int lo = f2h(tile[2 * cd][v]);
            unsigned int hi = f2h(tile[2 * cd + 1][v]);
            outu[(size_t)(n * DHW + v0 + v) * 32 + cd] = lo | (hi << 16);
        }
    } else {
        int f = (bid - 512) * 256 + t;   // 110592 total
        int i  = f & 7;
        int l  = (f >> 3) & 63;
        int wv = (f >> 9) & 3;
        int cc = (f >> 11) & 1;
        int k  = f >> 12;
        int o = wv * 16 + (l & 15);
        int c = cc * 32 + ((l >> 4) << 3) + i;
        wf[f] = f2h(w[(o * CC + c) * KN_ + k]);
    }
}

// ---------------------------------------------------------------------------
// Fused deformable sampling (f16 packed math) + f16 MFMA GEMM.
// MODE=0: grid NB*512,   all 27 taps, dst = final out.
// MODE=1: grid NB*512*2, k-halves [0,14)/[14,27), dst = partial buffers
//         (dst + half*OUT_ELEMS), summed by k_red afterwards.
template <int MODE>
__global__ __launch_bounds__(256, 8) void k_main(const unsigned short* __restrict__ inp,
                                                 const unsigned short* __restrict__ wf,
                                                 const float* __restrict__ offs,
                                                 float* __restrict__ dst) {
    __shared__ unsigned short S[2 * 32 * 64];   // [buf][p][c] f16, 16B-chunk XOR swizzle

    int t   = threadIdx.x;
    int bid = blockIdx.x;
    int half = MODE ? (bid >> 10) : 0;
    int n    = (bid >> 9) & 1;
    int p0   = (bid & 511) << 5;
    int k0   = half ? KSP : 0;
    int k1   = MODE ? (half ? KN_ : KSP) : KN_;
    float* base = dst + (size_t)half * OUT_ELEMS;

    // sampling role: one p per 8 lanes, 8-channel group per lane
    int sp = t >> 3;            // 0..31
    int cg = t & 7;             // channel-group (8 ch = 16 B)
    int pa = p0 + sp;
    int dpos = pa >> 10, hpos = (pa >> 5) & 31, wpos = pa & 31;

    // mfma role
    int wv = t >> 6, l = t & 63;
    int lrow = l & 15, lk = l >> 4;

    floatx4 acc0 = {0.f, 0.f, 0.f, 0.f};
    floatx4 acc1 = {0.f, 0.f, 0.f, 0.f};

    const float* offb = offs + (size_t)n * (3 * KN_) * DHW + pa;
    const unsigned short* inb = inp + ((size_t)n * DHW << 6);

    const int woff = sp * 64 + ((cg ^ (sp & 7)) << 3);
    const int prow1 = 16 + lrow;
    const int roff00 = lrow  * 64 + (((0 + lk) ^ (lrow  & 7)) << 3);
    const int roff10 = lrow  * 64 + (((4 + lk) ^ (lrow  & 7)) << 3);
    const int roff01 = prow1 * 64 + (((0 + lk) ^ (prow1 & 7)) << 3);
    const int roff11 = prow1 * 64 + (((4 + lk) ^ (prow1 & 7)) << 3);

    // offset prefetch (k0)
    float oz = offb[(k0 * 3 + 0) * DHW];
    float oy = offb[(k0 * 3 + 1) * DHW];
    float ox = offb[(k0 * 3 + 2) * DHW];

    for (int k = k0; k < k1; ++k) {
        // ---- prefetch next-k offsets (hide ~200cy load latency under this k) ----
        float noz = 0.f, noy = 0.f, nox = 0.f;
        if (k + 1 < k1) {
            noz = offb[((k + 1) * 3 + 0) * DHW];
            noy = offb[((k + 1) * 3 + 1) * DHW];
            nox = offb[((k + 1) * 3 + 2) * DHW];
        }

        // ---- W fragments (global, independent of LDS; issue early) ----
        const half8 wa0 = *(const half8*)(wf + (((k << 3) + 0 + wv) << 9) + (l << 3));
        const half8 wa1 = *(const half8*)(wf + (((k << 3) + 4 + wv) << 9) + (l << 3));

        // ---- sampling: 8 channels for (k, pa) ----
        float ix = ((float)wpos + ox) * (32.0f / 31.0f) - 0.5f;
        float iy = ((float)hpos + oy) * (32.0f / 31.0f) - 0.5f;
        float iz = ((float)dpos + oz) * (16.0f / 15.0f) - 0.5f;
        float xf = floorf(ix), yf = floorf(iy), zf = floorf(iz);
        float fx = ix - xf, fy = iy - yf, fz = iz - zf;
        int x0 = (int)xf, y0 = (int)yf, z0 = (int)zf;

        float wx0 = ((unsigned)x0       < (unsigned)WW) ? 1.f - fx : 0.f;
        float wx1 = ((unsigned)(x0 + 1) < (unsigned)WW) ? fx       : 0.f;
        float wy0 = ((unsigned)y0       < (unsigned)HH) ? 1.f - fy : 0.f;
        float wy1 = ((unsigned)(y0 + 1) < (unsigned)HH) ? fy       : 0.f;
        float wz0 = ((unsigned)z0       < (unsigned)DD) ? 1.f - fz : 0.f;
        float wz1 = ((unsigned)(z0 + 1) < (unsigned)DD) ? fz       : 0.f;

        int xc0 = min(max(x0, 0), WW - 1), xc1 = min(max(x0 + 1, 0), WW - 1);
        int yc0 = min(max(y0, 0), HH - 1), yc1 = min(max(y0 + 1, 0), HH - 1);
        int zc0 = min(max(z0, 0), DD - 1), zc1 = min(max(z0 + 1, 0), DD - 1);

        float wzy00 = wz0 * wy0, wzy01 = wz0 * wy1, wzy10 = wz1 * wy0, wzy11 = wz1 * wy1;
        int b00 = (zc0 * HH + yc0) * WW, b01 = (zc0 * HH + yc1) * WW;
        int b10 = (zc1 * HH + yc0) * WW, b11 = (zc1 * HH + yc1) * WW;

        const int vox[8] = {b00 + xc0, b00 + xc1, b01 + xc0, b01 + xc1,
                            b10 + xc0, b10 + xc1, b11 + xc0, b11 + xc1};
        const float cwt[8] = {wzy00 * wx0, wzy00 * wx1, wzy01 * wx0, wzy01 * wx1,
                              wzy10 * wx0, wzy10 * wx1, wzy11 * wx0, wzy11 * wx1};

        half8 acc = {0, 0, 0, 0, 0, 0, 0, 0};
#pragma unroll
        for (int cr = 0; cr < 8; ++cr) {
            const half8 v = *(const half8*)(inb + ((size_t)vox[cr] << 6) + (cg << 3));
            _Float16 wh = (_Float16)cwt[cr];
            half8 w8 = {wh, wh, wh, wh, wh, wh, wh, wh};
            acc += v * w8;     // 4x v_pk_fma_f16
        }
        *(half8*)(S + ((k & 1) << 11) + woff) = acc;

        oz = noz; oy = noy; ox = nox;

        __syncthreads();

        // ---- MFMA: acc[o16 x p16] over c=64 (two K=32 chunks) ----
        const unsigned short* Sb = S + ((k & 1) << 11);
        const half8 bf00 = *(const half8*)(Sb + roff00);
        const half8 bf10 = *(const half8*)(Sb + roff10);
        const half8 bf01 = *(const half8*)(Sb + roff01);
        const half8 bf11 = *(const half8*)(Sb + roff11);
        acc0 = __builtin_amdgcn_mfma_f32_16x16x32_f16(wa0, bf00, acc0, 0, 0, 0);
        acc0 = __builtin_amdgcn_mfma_f32_16x16x32_f16(wa1, bf10, acc0, 0, 0, 0);
        acc1 = __builtin_amdgcn_mfma_f32_16x16x32_f16(wa0, bf01, acc1, 0, 0, 0);
        acc1 = __builtin_amdgcn_mfma_f32_16x16x32_f16(wa1, bf11, acc1, 0, 0, 0);
        // double-buffered S: next iteration's barrier orders reads vs k+2 overwrite
    }

    // ---- epilogue: dst[n, o = wv*16 + lk*4 + r, p0 + lrow (+16)] ----
    float* ob = base + ((size_t)n * OC + (wv << 4) + (lk << 2)) * DHW + p0 + lrow;
#pragma unroll
    for (int r = 0; r < 4; ++r) {
        ob[r * DHW]      = acc0[r];
        ob[r * DHW + 16] = acc1[r];
    }
}

// ---------------------------------------------------------------------------
// Reduce: out = part0 + part1 (float4 per thread)
__global__ __launch_bounds__(256) void k_red(const float4* __restrict__ a,
                                             const float4* __restrict__ b,
                                             float4* __restrict__ o) {
    int i = blockIdx.x * 256 + threadIdx.x;
    float4 va = a[i], vb = b[i];
    float4 vo;
    vo.x = va.x + vb.x; vo.y = va.y + vb.y;
    vo.z = va.z + vb.z; vo.w = va.w + vb.w;
    o[i] = vo;
}

// ---------------------------------------------------------------------------
// Fallback (no workspace): fp32 fused kernel, original layouts.
__global__ __launch_bounds__(256) void k_fallback(const float* __restrict__ inp,
                                                  const float* __restrict__ wt,
                                                  const float* __restrict__ offs,
                                                  float* __restrict__ out) {
    __shared__ float Slds[64][68];
    __shared__ float Wlds[64 * 64];
    int bid = blockIdx.x;
    int n = bid >> 8;
    int p0 = (bid & 255) * 64;
    int t = threadIdx.x;
    int cq = t & 15, c0 = cq << 2, pslot = t >> 4;
    int ob = (t & 15) << 2, pb = (t >> 4) << 2;
    int swz_w = (((cq & 7) ^ (cq >> 3)) << 2);
    float acc[4][4] = {};
    const float* offbase = offs + (size_t)n * (KN_ * 3) * DHW;
    for (int k = 0; k < KN_; ++k) {
#pragma unroll
        for (int i = 0; i < 16; ++i) {
            int f = i * 256 + t;
            int o = f & 63, c = f >> 6;
            Wlds[f] = wt[(o * CC + c) * KN_ + k];
        }
#pragma unroll
        for (int j = 0; j < 4; ++j) {
            int pl = pslot + 16 * j;
            int pa = p0 + pl;
            int d = pa >> 10, h = (pa >> 5) & 31, w = pa & 31;
            float offz = offbase[(k * 3 + 0) * DHW + pa];
            float offy = offbase[(k * 3 + 1) * DHW + pa];
            float offx = offbase[(k * 3 + 2) * DHW + pa];
            float ix = ((float)w + offx) * (32.0f / 31.0f) - 0.5f;
            float iy = ((float)h + offy) * (32.0f / 31.0f) - 0.5f;
            float iz = ((float)d + offz) * (16.0f / 15.0f) - 0.5f;
            float xf = floorf(ix), yf = floorf(iy), zf = floorf(iz);
            float fx = ix - xf, fy = iy - yf, fz = iz - zf;
            int x0 = (int)xf, y0 = (int)yf, z0 = (int)zf;
            float wx0 = 1.0f - fx, wx1 = fx, wy0 = 1.0f - fy, wy1 = fy, wz0 = 1.0f - fz, wz1 = fz;
            float s0 = 0.f, s1 = 0.f, s2 = 0.f, s3 = 0.f;
#pragma unroll
            for (int dz = 0; dz < 2; ++dz) {
                int zc = z0 + dz;
                if ((unsigned)zc >= (unsigned)DD) continue;
                float wz = dz ? wz1 : wz0;
#pragma unroll
                for (int dy = 0; dy < 2; ++dy) {
                    int yc = y0 + dy;
                    if ((unsigned)yc >= (unsigned)HH) continue;
                    float wzy = wz * (dy ? wy1 : wy0);
#pragma unroll
                    for (int dx = 0; dx < 2; ++dx) {
                        int xc = x0 + dx;
                        if ((unsigned)xc >= (unsigned)WW) continue;
                        float wf = wzy * (dx ? wx1 : wx0);
                        int vox = (zc * HH + yc) * WW + xc;
                        const float* b = inp + (size_t)(n * CC + c0) * DHW + vox;
                        s0 += wf * b[0]; s1 += wf * b[DHW];
                        s2 += wf * b[2 * DHW]; s3 += wf * b[3 * DHW];
                    }
                }
            }
            int plw = pl ^ swz_w;
            Slds[c0 + 0][plw] = s0; Slds[c0 + 1][plw] = s1;
            Slds[c0 + 2][plw] = s2; Slds[c0 + 3][plw] = s3;
        }
        __syncthreads();
#pragma unroll
        for (int c = 0; c < 64; ++c) {
            const int g = ((c >> 2) & 7) ^ (c >> 5);
            float4 wv = *(const float4*)(Wlds + c * 64 + ob);
            float4 sv = *(const float4*)(&Slds[c][pb ^ (g << 2)]);
            float wa[4] = {wv.x, wv.y, wv.z, wv.w};
            float sa[4] = {sv.x, sv.y, sv.z, sv.w};
#pragma unroll
            for (int i = 0; i < 4; ++i)
#pragma unroll
                for (int jj = 0; jj < 4; ++jj) acc[i][jj] += wa[i] * sa[jj];
        }
        __syncthreads();
    }
#pragma unroll
    for (int i = 0; i < 4; ++i) {
        float4 vv;
        vv.x = acc[i][0]; vv.y = acc[i][1]; vv.z = acc[i][2]; vv.w = acc[i][3];
        *(float4*)(out + (size_t)(n * OC + ob + i) * DHW + p0 + pb) = vv;
    }
}

// ---------------------------------------------------------------------------
extern "C" void kernel_launch(void* const* d_in, const int* in_sizes, int n_in,
                              void* d_out, int out_size, void* d_ws, size_t ws_size,
                              hipStream_t stream) {
    const float* inp = (const float*)d_in[0];
    const float* off = (const float*)d_in[1];
    const float* wgt = (const float*)d_in[2];
    float* out = (float*)d_out;

    const size_t in_f16_bytes = (size_t)NB * DHW * CC * 2;           // 4 MB
    const size_t wf_bytes     = (size_t)KN_ * 2 * 4 * 64 * 8 * 2;    // 216 KB
    const size_t part_bytes   = OUT_ELEMS * sizeof(float);           // 8 MB
    const size_t need_small   = in_f16_bytes + wf_bytes;
    const size_t need_big     = need_small + 2 * part_bytes;         // ~21.2 MB

    if (ws_size >= need_small) {
        unsigned int*   in_t = (unsigned int*)d_ws;
        unsigned short* w_f  = (unsigned short*)((char*)d_ws + in_f16_bytes);
        k_prep<<<dim3(512 + 432), dim3(256), 0, stream>>>(inp, wgt, in_t, w_f);
        if (ws_size >= need_big) {
            float* part = (float*)((char*)d_ws + need_small);
            k_main<1><<<dim3(NB * 512 * 2), dim3(256), 0, stream>>>(
                (const unsigned short*)in_t, w_f, off, part);
            k_red<<<dim3((int)(OUT_ELEMS / 4 / 256)), dim3(256), 0, stream>>>(
                (const float4*)part, (const float4*)(part + OUT_ELEMS), (float4*)out);
        } else {
            k_main<0><<<dim3(NB * 512), dim3(256), 0, stream>>>(
                (const unsigned short*)in_t, w_f, off, out);
        }
    } else {
        k_fallback<<<dim3(NB * 256), dim3(256), 0, stream>>>(inp, wgt, off, out);
    }
}

// Round 5
// 113.888 us; speedup vs baseline: 1.0744x; 1.0744x over previous
//
#include <hip/hip_runtime.h>

typedef __attribute__((ext_vector_type(8))) _Float16 half8;
typedef __attribute__((ext_vector_type(4))) float floatx4;

constexpr int NB  = 2;
constexpr int CC  = 64;
constexpr int DD  = 16;
constexpr int HH  = 32;
constexpr int WW  = 32;
constexpr int KN_ = 27;
constexpr int OC  = 64;
constexpr int DHW = DD * HH * WW;   // 16384
constexpr int TP  = 16;             // positions per block
constexpr int KCH = 9;              // taps per setup chunk (3 chunks of 9)

__device__ __forceinline__ unsigned short f2h(float f) {
    _Float16 h = (_Float16)f;
    return *(unsigned short*)&h;
}

// ---------------------------------------------------------------------------
// Prep kernel (merged):
//  blocks [0, 512)   : NCDHW f32 -> NDHWC f16  (64 ch contiguous per voxel)
//  blocks [512, 944) : weight (o,c,k) f32 -> f16 MFMA A-fragment stream
//    wf[(((k*2+cc)*4+ot)*64 + l)*8 + i] = W[o=ot*16+(l&15)][c=cc*32+(l>>4)*8+i][k]
__global__ __launch_bounds__(256) void k_prep(const float* __restrict__ in,
                                              const float* __restrict__ w,
                                              unsigned int* __restrict__ outu,
                                              unsigned short* __restrict__ wf) {
    int bid = blockIdx.x;
    int t = threadIdx.x;
    if (bid < 512) {
        __shared__ float tile[64][65];
        int n  = bid >> 8;
        int v0 = (bid & 255) << 6;
        int lane = t & 63, row = t >> 6;
#pragma unroll
        for (int i = 0; i < 16; ++i) {
            int c = (i << 2) + row;
            tile[c][lane] = in[(size_t)(n * CC + c) * DHW + v0 + lane];
        }
        __syncthreads();
#pragma unroll
        for (int i = 0; i < 8; ++i) {
            int flat = i * 256 + t;
            int v = flat >> 5, cd = flat & 31;
            unsigned int lo = f2h(tile[2 * cd][v]);
            unsigned int hi = f2h(tile[2 * cd + 1][v]);
            outu[(size_t)(n * DHW + v0 + v) * 32 + cd] = lo | (hi << 16);
        }
    } else {
        int f = (bid - 512) * 256 + t;   // 110592 total
        int i  = f & 7;
        int l  = (f >> 3) & 63;
        int ot = (f >> 9) & 3;
        int cc = (f >> 11) & 1;
        int k  = f >> 12;
        int o = ot * 16 + (l & 15);
        int c = cc * 32 + ((l >> 4) << 3) + i;
        wf[f] = f2h(w[(o * CC + c) * KN_ + k]);
    }
}

// ---------------------------------------------------------------------------
// Fused deformable sampling + f16 MFMA GEMM, setup-in-LDS.
// Grid: NB*1024 blocks of 128 threads; each block: 16 positions, all 27 taps.
// Block->XCD mapping puts batch n on a fixed XCD half (L2 locality).
__global__ __launch_bounds__(128, 6) void k_main(const unsigned short* __restrict__ inp,
                                                 const unsigned short* __restrict__ wf,
                                                 const float* __restrict__ offs,
                                                 float* __restrict__ out) {
    __shared__ unsigned short S[2 * TP * 64];       // 4KB dbuf [buf][p][c] f16, chunk-XOR swz
    __shared__ unsigned int   SU[KCH * TP * 12];    // 6.9KB setup: 48B rec = {u16 vox[8], f16 w[8], pad}

    int t   = threadIdx.x;
    int bid = blockIdx.x;
    int n   = (bid >> 2) & 1;                       // XCD bit2 selects batch
    int idx = ((bid >> 3) << 2) | (bid & 3);        // 0..1023
    int p0  = idx << 4;

    // sampling role: 16 groups of 8 lanes; lane handles 8 channels (16B)
    int sp = t >> 3;            // 0..15 position in tile
    int cg = t & 7;             // channel chunk
    // mfma role
    int wv = t >> 6, l = t & 63;
    int lrow = l & 15, lk = l >> 4;

    const float* offb = offs + (size_t)n * (3 * KN_) * DHW + p0;
    const char*  inb  = (const char*)(inp + ((size_t)n * DHW << 6));

    floatx4 acc0 = {0.f, 0.f, 0.f, 0.f};
    floatx4 acc1 = {0.f, 0.f, 0.f, 0.f};

    const int cgo   = cg << 4;                                  // byte offset in 128B voxel row
    const int woff  = sp * 64 + ((cg ^ (sp & 7)) << 3);         // ushort units
    const int roff0 = lrow * 64 + (((0 | lk) ^ (lrow & 7)) << 3);
    const int roff1 = lrow * 64 + (((4 | lk) ^ (lrow & 7)) << 3);

    for (int ch = 0; ch < 3; ++ch) {
        __syncthreads();   // all reads of previous SU chunk (and last S buf) done

        // ---- setup fill: 144 records (kk,p), coordinate math ONCE per record ----
        for (int si = t; si < KCH * TP; si += 128) {
            int kk = si >> 4, p = si & 15;
            int k  = ch * KCH + kk;
            int pa = p0 + p;
            int dpos = pa >> 10, hpos = (pa >> 5) & 31, wpos = pa & 31;

            float oz = offb[(k * 3 + 0) * DHW + p];
            float oy = offb[(k * 3 + 1) * DHW + p];
            float ox = offb[(k * 3 + 2) * DHW + p];
            float ix = ((float)wpos + ox) * (32.0f / 31.0f) - 0.5f;
            float iy = ((float)hpos + oy) * (32.0f / 31.0f) - 0.5f;
            float iz = ((float)dpos + oz) * (16.0f / 15.0f) - 0.5f;
            float xf = floorf(ix), yf = floorf(iy), zf = floorf(iz);
            float fx = ix - xf, fy = iy - yf, fz = iz - zf;
            int x0 = (int)xf, y0 = (int)yf, z0 = (int)zf;

            float wx0 = ((unsigned)x0       < (unsigned)WW) ? 1.f - fx : 0.f;
            float wx1 = ((unsigned)(x0 + 1) < (unsigned)WW) ? fx       : 0.f;
            float wy0 = ((unsigned)y0       < (unsigned)HH) ? 1.f - fy : 0.f;
            float wy1 = ((unsigned)(y0 + 1) < (unsigned)HH) ? fy       : 0.f;
            float wz0 = ((unsigned)z0       < (unsigned)DD) ? 1.f - fz : 0.f;
            float wz1 = ((unsigned)(z0 + 1) < (unsigned)DD) ? fz       : 0.f;

            int xc0 = min(max(x0, 0), WW - 1), xc1 = min(max(x0 + 1, 0), WW - 1);
            int yc0 = min(max(y0, 0), HH - 1), yc1 = min(max(y0 + 1, 0), HH - 1);
            int zc0 = min(max(z0, 0), DD - 1), zc1 = min(max(z0 + 1, 0), DD - 1);

            float wzy00 = wz0 * wy0, wzy01 = wz0 * wy1, wzy10 = wz1 * wy0, wzy11 = wz1 * wy1;
            unsigned int b00 = (zc0 * HH + yc0) * WW, b01 = (zc0 * HH + yc1) * WW;
            unsigned int b10 = (zc1 * HH + yc0) * WW, b11 = (zc1 * HH + yc1) * WW;

            uint4 vp, wp;
            vp.x = (b00 + xc0) | ((b00 + xc1) << 16);
            vp.y = (b01 + xc0) | ((b01 + xc1) << 16);
            vp.z = (b10 + xc0) | ((b10 + xc1) << 16);
            vp.w = (b11 + xc0) | ((b11 + xc1) << 16);
            wp.x = (unsigned int)f2h(wzy00 * wx0) | ((unsigned int)f2h(wzy00 * wx1) << 16);
            wp.y = (unsigned int)f2h(wzy01 * wx0) | ((unsigned int)f2h(wzy01 * wx1) << 16);
            wp.z = (unsigned int)f2h(wzy10 * wx0) | ((unsigned int)f2h(wzy10 * wx1) << 16);
            wp.w = (unsigned int)f2h(wzy11 * wx0) | ((unsigned int)f2h(wzy11 * wx1) << 16);

            unsigned int* rec = SU + si * 12;
            *(uint4*)rec       = vp;
            *(uint4*)(rec + 4) = wp;
        }
        __syncthreads();

        // ---- gather + GEMM over this k-chunk ----
        for (int kk = 0; kk < KCH; ++kk) {
            int k = ch * KCH + kk;

            // W fragments (L2-resident stream; issue early)
            const half8 wa00 = *(const half8*)(wf + ((((k << 1) | 0) * 4 + (wv << 1) + 0) << 9) + (l << 3));
            const half8 wa01 = *(const half8*)(wf + ((((k << 1) | 1) * 4 + (wv << 1) + 0) << 9) + (l << 3));
            const half8 wa10 = *(const half8*)(wf + ((((k << 1) | 0) * 4 + (wv << 1) + 1) << 9) + (l << 3));
            const half8 wa11 = *(const half8*)(wf + ((((k << 1) | 1) * 4 + (wv << 1) + 1) << 9) + (l << 3));

            // setup record (8 lanes of a group broadcast-read the same 32B)
            const unsigned int* rec = SU + (kk * TP + sp) * 12;
            const uint4 vp = *(const uint4*)rec;
            const uint4 wp = *(const uint4*)(rec + 4);
            const unsigned int vpa[4] = {vp.x, vp.y, vp.z, vp.w};
            const unsigned int wpa[4] = {wp.x, wp.y, wp.z, wp.w};

            half8 accv = {0, 0, 0, 0, 0, 0, 0, 0};
#pragma unroll
            for (int cr = 0; cr < 8; ++cr) {
                unsigned int vd = vpa[cr >> 1];
                unsigned int wd = wpa[cr >> 1];
                unsigned int voxb = ((cr & 1) ? (vd >> 16) : (vd & 0xffffu)) << 7;
                unsigned short wu = (cr & 1) ? (unsigned short)(wd >> 16) : (unsigned short)wd;
                _Float16 wh = *(_Float16*)&wu;
                const half8 v = *(const half8*)(inb + voxb + cgo);
                half8 w8 = {wh, wh, wh, wh, wh, wh, wh, wh};
                accv += v * w8;                      // 4x v_pk_fma_f16
            }
            *(half8*)(S + ((k & 1) << 10) + woff) = accv;

            __syncthreads();

            // MFMA: D[o16 x p16] += A(o x c) * B(c x p), two c-chunks of 32
            const unsigned short* Sb = S + ((k & 1) << 10);
            const half8 bf0 = *(const half8*)(Sb + roff0);
            const half8 bf1 = *(const half8*)(Sb + roff1);
            acc0 = __builtin_amdgcn_mfma_f32_16x16x32_f16(wa00, bf0, acc0, 0, 0, 0);
            acc0 = __builtin_amdgcn_mfma_f32_16x16x32_f16(wa01, bf1, acc0, 0, 0, 0);
            acc1 = __builtin_amdgcn_mfma_f32_16x16x32_f16(wa10, bf0, acc1, 0, 0, 0);
            acc1 = __builtin_amdgcn_mfma_f32_16x16x32_f16(wa11, bf1, acc1, 0, 0, 0);
            // dbuf S: next iteration's barrier orders reads vs k+2 overwrite
        }
    }

    // ---- epilogue: o = wv*32 + (acc sel)*16 + lk*4 + r ; p = p0 + lrow ----
    float* ob = out + ((size_t)n * OC + (wv << 5) + (lk << 2)) * DHW + p0 + lrow;
#pragma unroll
    for (int r = 0; r < 4; ++r) {
        ob[r * DHW]              = acc0[r];
        ob[r * DHW + (DHW << 4)] = acc1[r];
    }
}

// ---------------------------------------------------------------------------
// Fallback (no workspace): fp32 fused kernel, original layouts.
__global__ __launch_bounds__(256) void k_fallback(const float* __restrict__ inp,
                                                  const float* __restrict__ wt,
                                                  const float* __restrict__ offs,
                                                  float* __restrict__ out) {
    __shared__ float Slds[64][68];
    __shared__ float Wlds[64 * 64];
    int bid = blockIdx.x;
    int n = bid >> 8;
    int p0 = (bid & 255) * 64;
    int t = threadIdx.x;
    int cq = t & 15, c0 = cq << 2, pslot = t >> 4;
    int ob = (t & 15) << 2, pb = (t >> 4) << 2;
    int swz_w = (((cq & 7) ^ (cq >> 3)) << 2);
    float acc[4][4] = {};
    const float* offbase = offs + (size_t)n * (KN_ * 3) * DHW;
    for (int k = 0; k < KN_; ++k) {
#pragma unroll
        for (int i = 0; i < 16; ++i) {
            int f = i * 256 + t;
            int o = f & 63, c = f >> 6;
            Wlds[f] = wt[(o * CC + c) * KN_ + k];
        }
#pragma unroll
        for (int j = 0; j < 4; ++j) {
            int pl = pslot + 16 * j;
            int pa = p0 + pl;
            int d = pa >> 10, h = (pa >> 5) & 31, w = pa & 31;
            float offz = offbase[(k * 3 + 0) * DHW + pa];
            float offy = offbase[(k * 3 + 1) * DHW + pa];
            float offx = offbase[(k * 3 + 2) * DHW + pa];
            float ix = ((float)w + offx) * (32.0f / 31.0f) - 0.5f;
            float iy = ((float)h + offy) * (32.0f / 31.0f) - 0.5f;
            float iz = ((float)d + offz) * (16.0f / 15.0f) - 0.5f;
            float xf = floorf(ix), yf = floorf(iy), zf = floorf(iz);
            float fx = ix - xf, fy = iy - yf, fz = iz - zf;
            int x0 = (int)xf, y0 = (int)yf, z0 = (int)zf;
            float wx0 = 1.0f - fx, wx1 = fx, wy0 = 1.0f - fy, wy1 = fy, wz0 = 1.0f - fz, wz1 = fz;
            float s0 = 0.f, s1 = 0.f, s2 = 0.f, s3 = 0.f;
#pragma unroll
            for (int dz = 0; dz < 2; ++dz) {
                int zc = z0 + dz;
                if ((unsigned)zc >= (unsigned)DD) continue;
                float wz = dz ? wz1 : wz0;
#pragma unroll
                for (int dy = 0; dy < 2; ++dy) {
                    int yc = y0 + dy;
                    if ((unsigned)yc >= (unsigned)HH) continue;
                    float wzy = wz * (dy ? wy1 : wy0);
#pragma unroll
                    for (int dx = 0; dx < 2; ++dx) {
                        int xc = x0 + dx;
                        if ((unsigned)xc >= (unsigned)WW) continue;
                        float wf = wzy * (dx ? wx1 : wx0);
                        int vox = (zc * HH + yc) * WW + xc;
                        const float* b = inp + (size_t)(n * CC + c0) * DHW + vox;
                        s0 += wf * b[0]; s1 += wf * b[DHW];
                        s2 += wf * b[2 * DHW]; s3 += wf * b[3 * DHW];
                    }
                }
            }
            int plw = pl ^ swz_w;
            Slds[c0 + 0][plw] = s0; Slds[c0 + 1][plw] = s1;
            Slds[c0 + 2][plw] = s2; Slds[c0 + 3][plw] = s3;
        }
        __syncthreads();
#pragma unroll
        for (int c = 0; c < 64; ++c) {
            const int g = ((c >> 2) & 7) ^ (c >> 5);
            float4 wv = *(const float4*)(Wlds + c * 64 + ob);
            float4 sv = *(const float4*)(&Slds[c][pb ^ (g << 2)]);
            float wa[4] = {wv.x, wv.y, wv.z, wv.w};
            float sa[4] = {sv.x, sv.y, sv.z, sv.w};
#pragma unroll
            for (int i = 0; i < 4; ++i)
#pragma unroll
                for (int jj = 0; jj < 4; ++jj) acc[i][jj] += wa[i] * sa[jj];
        }
        __syncthreads();
    }
#pragma unroll
    for (int i = 0; i < 4; ++i) {
        float4 vv;
        vv.x = acc[i][0]; vv.y = acc[i][1]; vv.z = acc[i][2]; vv.w = acc[i][3];
        *(float4*)(out + (size_t)(n * OC + ob + i) * DHW + p0 + pb) = vv;
    }
}

// ---------------------------------------------------------------------------
extern "C" void kernel_launch(void* const* d_in, const int* in_sizes, int n_in,
                              void* d_out, int out_size, void* d_ws, size_t ws_size,
                              hipStream_t stream) {
    const float* inp = (const float*)d_in[0];
    const float* off = (const float*)d_in[1];
    const float* wgt = (const float*)d_in[2];
    float* out = (float*)d_out;

    const size_t in_f16_bytes = (size_t)NB * DHW * CC * 2;           // 4 MB
    const size_t wf_bytes     = (size_t)KN_ * 2 * 4 * 64 * 8 * 2;    // 216 KB

    if (ws_size >= in_f16_bytes + wf_bytes) {
        unsigned int*   in_t = (unsigned int*)d_ws;
        unsigned short* w_f  = (unsigned short*)((char*)d_ws + in_f16_bytes);
        k_prep<<<dim3(512 + 432), dim3(256), 0, stream>>>(inp, wgt, in_t, w_f);
        k_main<<<dim3(NB * 1024), dim3(128), 0, stream>>>(
            (const unsigned short*)in_t, w_f, off, out);
    } else {
        k_fallback<<<dim3(NB * 256), dim3(256), 0, stream>>>(inp, wgt, off, out);
    }
}